// Round 2
// baseline (40.959 us; speedup 1.0000x reference)
//
#include <hip/hip_runtime.h>
#include <math.h>

// f(x) = tanh-MLP(x), layers 1->16->32->32->16->3, applied per scalar element.
// Kernel 1: tabulate f on a TN-point grid into d_ws.
// Kernel 2: output-float4-major lerp — each thread produces one out float4
// (floats 4g..4g+3), needing exactly elements e=(4g)/3 and e+1. One fully
// coalesced 16B/lane store per thread (the R1 kernel's 48B-strided stores
// were a ~3x write-path amplification).

#define TN 2048
#define XLO (-10.0f)
#define XHI (10.0f)

__device__ __forceinline__ float fast_tanh(float x) {
    float t = __builtin_amdgcn_exp2f(x * 2.885390081777927f);
    return 1.0f - 2.0f * __builtin_amdgcn_rcpf(t + 1.0f);
}

__global__ __launch_bounds__(256) void build_table(
    const float* __restrict__ W0, const float* __restrict__ b0,
    const float* __restrict__ W1, const float* __restrict__ b1,
    const float* __restrict__ W2, const float* __restrict__ b2,
    const float* __restrict__ W3, const float* __restrict__ b3,
    const float* __restrict__ W4, const float* __restrict__ b4,
    float4* __restrict__ table)
{
    int i = blockIdx.x * 256 + threadIdx.x;
    if (i >= TN) return;
    const float h = (XHI - XLO) / (float)(TN - 1);
    float x = XLO + (float)i * h;

    float a[32], c[32];
    #pragma unroll
    for (int j = 0; j < 16; ++j) a[j] = fast_tanh(fmaf(x, W0[j], b0[j]));
    #pragma unroll
    for (int j = 0; j < 32; ++j) {
        float acc = b1[j];
        #pragma unroll
        for (int k = 0; k < 16; ++k) acc = fmaf(a[k], W1[k * 32 + j], acc);
        c[j] = fast_tanh(acc);
    }
    #pragma unroll
    for (int j = 0; j < 32; ++j) {
        float acc = b2[j];
        #pragma unroll
        for (int k = 0; k < 32; ++k) acc = fmaf(c[k], W2[k * 32 + j], acc);
        a[j] = fast_tanh(acc);
    }
    #pragma unroll
    for (int j = 0; j < 16; ++j) {
        float acc = b3[j];
        #pragma unroll
        for (int k = 0; k < 32; ++k) acc = fmaf(a[k], W3[k * 16 + j], acc);
        c[j] = fast_tanh(acc);
    }
    float o[3];
    #pragma unroll
    for (int j = 0; j < 3; ++j) {
        float acc = b4[j];
        #pragma unroll
        for (int k = 0; k < 16; ++k) acc = fmaf(c[k], W4[k * 3 + j], acc);
        o[j] = fast_tanh(acc);
    }
    table[i] = make_float4(o[0], o[1], o[2], 0.0f);
}

__device__ __forceinline__ void lerp3(const float4* __restrict__ tab,
                                      float inv_h, float x,
                                      float& r0, float& r1, float& r2)
{
    float xc = fminf(fmaxf(x, XLO), XHI);
    float f  = (xc - XLO) * inv_h;
    int i0 = (int)f;
    i0 = min(i0, TN - 2);
    float fr = f - (float)i0;
    float4 t0 = tab[i0];
    float4 t1 = tab[i0 + 1];
    r0 = fmaf(fr, t1.x - t0.x, t0.x);
    r1 = fmaf(fr, t1.y - t0.y, t0.y);
    r2 = fmaf(fr, t1.z - t0.z, t0.z);
}

__global__ __launch_bounds__(256) void apply_table(
    const float* __restrict__ x, const float4* __restrict__ tab_g,
    float4* __restrict__ out4, unsigned n_out4)
{
    __shared__ float4 tab[TN];   // 32 KB -> 5 blocks/CU
    for (int i = threadIdx.x; i < TN; i += 256) tab[i] = tab_g[i];
    __syncthreads();

    const float inv_h = (float)(TN - 1) / (XHI - XLO);
    unsigned stride = gridDim.x * 256u;
    for (unsigned g = blockIdx.x * 256u + threadIdx.x; g < n_out4; g += stride) {
        // out floats 4g..4g+3 come from elements e and e+1
        unsigned e = (4u * g) / 3u;
        unsigned r = 4u * g - 3u * e;        // 0,1,2
        float x0 = x[e];
        float x1 = x[e + 1];
        float s0, s1, s2, s3, s4, s5;
        lerp3(tab, inv_h, x0, s0, s1, s2);
        lerp3(tab, inv_h, x1, s3, s4, s5);
        // window [r..r+3] of (s0..s5), selected without runtime indexing
        float4 o;
        o.x = (r == 0u) ? s0 : ((r == 1u) ? s1 : s2);
        o.y = (r == 0u) ? s1 : ((r == 1u) ? s2 : s3);
        o.z = (r == 0u) ? s2 : ((r == 1u) ? s3 : s4);
        o.w = (r == 0u) ? s3 : ((r == 1u) ? s4 : s5);
        out4[g] = o;
    }
}

extern "C" void kernel_launch(void* const* d_in, const int* in_sizes, int n_in,
                              void* d_out, int out_size, void* d_ws, size_t ws_size,
                              hipStream_t stream) {
    const float* x  = (const float*)d_in[0];
    const float* W0 = (const float*)d_in[1];
    const float* b0 = (const float*)d_in[2];
    const float* W1 = (const float*)d_in[3];
    const float* b1 = (const float*)d_in[4];
    const float* W2 = (const float*)d_in[5];
    const float* b2 = (const float*)d_in[6];
    const float* W3 = (const float*)d_in[7];
    const float* b3 = (const float*)d_in[8];
    const float* W4 = (const float*)d_in[9];
    const float* b4 = (const float*)d_in[10];
    float4* table = (float4*)d_ws;   // TN*16 = 32 KB scratch

    build_table<<<(TN + 255) / 256, 256, 0, stream>>>(
        W0, b0, W1, b1, W2, b2, W3, b3, W4, b4, table);

    unsigned n_out4 = (unsigned)out_size / 4u;   // 3145728
    int blocks = 1280;                           // 5 blocks/CU (LDS-capped)
    apply_table<<<blocks, 256, 0, stream>>>(
        x, table, (float4*)d_out, n_out4);
}

// Round 3
// 40.684 us; speedup vs baseline: 1.0068x; 1.0068x over previous
//
#include <hip/hip_runtime.h>
#include <math.h>

// f(x) = tanh-MLP(x), layers 1->16->32->32->16->3, applied per scalar element.
// Kernel 1 (build_table): tabulate f on TN grid points. Weights staged into
//   LDS *transposed* (output-neuron-major) so each dot product is contiguous
//   float4 reads; 32 blocks x 64 lanes (R2's version was latency-bound on
//   ~2100 uniform global weight loads with only 8 blocks -> ~30us hidden cost).
// Kernel 2 (apply_table): output-float4-major lerp, one coalesced 16B store
//   per thread, table staged in LDS.

#define TN 2048
#define XLO (-10.0f)
#define XHI (10.0f)

__device__ __forceinline__ float fast_tanh(float x) {
    float t = __builtin_amdgcn_exp2f(x * 2.885390081777927f);
    return 1.0f - 2.0f * __builtin_amdgcn_rcpf(t + 1.0f);
}

// LDS float layout (all row starts 16B-aligned):
//   W0t   [16]        @ 0      (j contiguous)
//   B0    [16]        @ 16
//   W1t   [32][16]    @ 32     row j @ 32   + j*16
//   B1    [32]        @ 544
//   W2t   [32][32]    @ 576    row j @ 576  + j*32
//   B2    [32]        @ 1600
//   W3t   [16][32]    @ 1632   row j @ 1632 + j*32
//   B3    [16]        @ 2144
//   W4t   [3][16]     @ 2160   row j @ 2160 + j*16
//   B4    [3]         @ 2208
__global__ __launch_bounds__(64) void build_table(
    const float* __restrict__ W0, const float* __restrict__ b0,
    const float* __restrict__ W1, const float* __restrict__ b1,
    const float* __restrict__ W2, const float* __restrict__ b2,
    const float* __restrict__ W3, const float* __restrict__ b3,
    const float* __restrict__ W4, const float* __restrict__ b4,
    float4* __restrict__ table)
{
    __shared__ __align__(16) float w[2224];
    const int t = threadIdx.x;

    for (int i = t; i < 16; i += 64) { w[i] = W0[i]; w[16 + i] = b0[i]; }
    for (int i = t; i < 512; i += 64) { int k = i >> 5, j = i & 31; w[32   + j * 16 + k] = W1[i]; }
    for (int i = t; i < 32;  i += 64) w[544  + i] = b1[i];
    for (int i = t; i < 1024; i += 64){ int k = i >> 5, j = i & 31; w[576  + j * 32 + k] = W2[i]; }
    for (int i = t; i < 32;  i += 64) w[1600 + i] = b2[i];
    for (int i = t; i < 512; i += 64) { int k = i >> 4, j = i & 15; w[1632 + j * 32 + k] = W3[i]; }
    for (int i = t; i < 16;  i += 64) w[2144 + i] = b3[i];
    for (int i = t; i < 48;  i += 64) { int k = i / 3, j = i - 3 * k; w[2160 + j * 16 + k] = W4[i]; }
    if (t < 3) w[2208 + t] = b4[t];
    __syncthreads();

    const int pi = blockIdx.x * 64 + t;          // table point index, < TN
    const float h = (XHI - XLO) / (float)(TN - 1);
    const float x = XLO + (float)pi * h;
    const float4* L4 = (const float4*)w;

    float a[32], c[32];
    // L0: 1 -> 16
    #pragma unroll
    for (int q = 0; q < 4; ++q) {
        float4 wq = L4[q];
        float4 bq = L4[4 + q];
        a[4 * q + 0] = fast_tanh(fmaf(x, wq.x, bq.x));
        a[4 * q + 1] = fast_tanh(fmaf(x, wq.y, bq.y));
        a[4 * q + 2] = fast_tanh(fmaf(x, wq.z, bq.z));
        a[4 * q + 3] = fast_tanh(fmaf(x, wq.w, bq.w));
    }
    // L1: 16 -> 32
    #pragma unroll
    for (int j = 0; j < 32; ++j) {
        float acc = w[544 + j];
        #pragma unroll
        for (int q = 0; q < 4; ++q) {
            float4 wq = L4[8 + j * 4 + q];
            acc = fmaf(a[4 * q + 0], wq.x, acc);
            acc = fmaf(a[4 * q + 1], wq.y, acc);
            acc = fmaf(a[4 * q + 2], wq.z, acc);
            acc = fmaf(a[4 * q + 3], wq.w, acc);
        }
        c[j] = fast_tanh(acc);
    }
    // L2: 32 -> 32
    #pragma unroll
    for (int j = 0; j < 32; ++j) {
        float acc = w[1600 + j];
        #pragma unroll
        for (int q = 0; q < 8; ++q) {
            float4 wq = L4[144 + j * 8 + q];
            acc = fmaf(c[4 * q + 0], wq.x, acc);
            acc = fmaf(c[4 * q + 1], wq.y, acc);
            acc = fmaf(c[4 * q + 2], wq.z, acc);
            acc = fmaf(c[4 * q + 3], wq.w, acc);
        }
        a[j] = fast_tanh(acc);
    }
    // L3: 32 -> 16
    #pragma unroll
    for (int j = 0; j < 16; ++j) {
        float acc = w[2144 + j];
        #pragma unroll
        for (int q = 0; q < 8; ++q) {
            float4 wq = L4[408 + j * 8 + q];
            acc = fmaf(a[4 * q + 0], wq.x, acc);
            acc = fmaf(a[4 * q + 1], wq.y, acc);
            acc = fmaf(a[4 * q + 2], wq.z, acc);
            acc = fmaf(a[4 * q + 3], wq.w, acc);
        }
        c[j] = fast_tanh(acc);
    }
    // L4: 16 -> 3
    float o[3];
    #pragma unroll
    for (int j = 0; j < 3; ++j) {
        float acc = w[2208 + j];
        #pragma unroll
        for (int q = 0; q < 4; ++q) {
            float4 wq = L4[540 + j * 4 + q];
            acc = fmaf(c[4 * q + 0], wq.x, acc);
            acc = fmaf(c[4 * q + 1], wq.y, acc);
            acc = fmaf(c[4 * q + 2], wq.z, acc);
            acc = fmaf(c[4 * q + 3], wq.w, acc);
        }
        o[j] = fast_tanh(acc);
    }
    table[pi] = make_float4(o[0], o[1], o[2], 0.0f);
}

__device__ __forceinline__ void lerp3(const float4* __restrict__ tab,
                                      float inv_h, float x,
                                      float& r0, float& r1, float& r2)
{
    float xc = fminf(fmaxf(x, XLO), XHI);
    float f  = (xc - XLO) * inv_h;
    int i0 = (int)f;
    i0 = min(i0, TN - 2);
    float fr = f - (float)i0;
    float4 t0 = tab[i0];
    float4 t1 = tab[i0 + 1];
    r0 = fmaf(fr, t1.x - t0.x, t0.x);
    r1 = fmaf(fr, t1.y - t0.y, t0.y);
    r2 = fmaf(fr, t1.z - t0.z, t0.z);
}

__global__ __launch_bounds__(256) void apply_table(
    const float* __restrict__ x, const float4* __restrict__ tab_g,
    float4* __restrict__ out4, unsigned n_out4)
{
    __shared__ float4 tab[TN];   // 32 KB -> 5 blocks/CU
    for (int i = threadIdx.x; i < TN; i += 256) tab[i] = tab_g[i];
    __syncthreads();

    const float inv_h = (float)(TN - 1) / (XHI - XLO);
    unsigned stride = gridDim.x * 256u;
    for (unsigned g = blockIdx.x * 256u + threadIdx.x; g < n_out4; g += stride) {
        unsigned e = (4u * g) / 3u;          // first input element needed
        unsigned r = 4u * g - 3u * e;        // 0,1,2
        float x0 = x[e];
        float x1 = x[e + 1];
        float s0, s1, s2, s3, s4, s5;
        lerp3(tab, inv_h, x0, s0, s1, s2);
        lerp3(tab, inv_h, x1, s3, s4, s5);
        float4 o;
        o.x = (r == 0u) ? s0 : ((r == 1u) ? s1 : s2);
        o.y = (r == 0u) ? s1 : ((r == 1u) ? s2 : s3);
        o.z = (r == 0u) ? s2 : ((r == 1u) ? s3 : s4);
        o.w = (r == 0u) ? s3 : ((r == 1u) ? s4 : s5);
        out4[g] = o;
    }
}

extern "C" void kernel_launch(void* const* d_in, const int* in_sizes, int n_in,
                              void* d_out, int out_size, void* d_ws, size_t ws_size,
                              hipStream_t stream) {
    const float* x  = (const float*)d_in[0];
    const float* W0 = (const float*)d_in[1];
    const float* b0 = (const float*)d_in[2];
    const float* W1 = (const float*)d_in[3];
    const float* b1 = (const float*)d_in[4];
    const float* W2 = (const float*)d_in[5];
    const float* b2 = (const float*)d_in[6];
    const float* W3 = (const float*)d_in[7];
    const float* b3 = (const float*)d_in[8];
    const float* W4 = (const float*)d_in[9];
    const float* b4 = (const float*)d_in[10];
    float4* table = (float4*)d_ws;   // TN*16 = 32 KB scratch

    build_table<<<TN / 64, 64, 0, stream>>>(
        W0, b0, W1, b1, W2, b2, W3, b3, W4, b4, table);

    unsigned n_out4 = (unsigned)out_size / 4u;   // 3145728
    int blocks = 1280;                           // 5 blocks/CU (LDS-capped)
    apply_table<<<blocks, 256, 0, stream>>>(
        x, table, (float4*)d_out, n_out4);
}